// Round 8
// baseline (558.145 us; speedup 1.0000x reference)
//
#include <hip/hip_runtime.h>
#include <hip/hip_bf16.h>

typedef unsigned short u16;
typedef __attribute__((ext_vector_type(8))) short bf16x8;   // 8 bf16 (4 VGPRs)
typedef __attribute__((ext_vector_type(4))) float f32x4;

#define Bdim 4
#define Nseq 2048
#define DIMc 1024
#define NH   16
#define HD   64
#define F3   3072   // 3*NH*HD
#define Mrows 8192  // Bdim*Nseq

#define KPAD 68     // LDS row stride in u16: 136 B = 34 dwords -> 2-way banks (free)

typedef const __attribute__((address_space(1))) unsigned int gl_u32;
typedef __attribute__((address_space(3))) unsigned int lds_u32;

// f32 -> bf16 RNE
static __device__ __forceinline__ u16 f2b(float f) {
    union { float f; unsigned u; } v; v.f = f;
    unsigned r = v.u + 0x7fffu + ((v.u >> 16) & 1u);
    return (u16)(r >> 16);
}

__global__ __launch_bounds__(256) void cast_f32_bf16_kernel(const float* __restrict__ in,
                                                            u16* __restrict__ out, int n4) {
    int i = blockIdx.x * 256 + threadIdx.x;
    if (i >= n4) return;
    float4 v = reinterpret_cast<const float4*>(in)[i];
    ushort4 o;
    o.x = f2b(v.x); o.y = f2b(v.y); o.z = f2b(v.z); o.w = f2b(v.w);
    reinterpret_cast<ushort4*>(out)[i] = o;
}

// Normalize a 0/1 mask buffer of unknown dtype (int32 / float32 / uint8) to int32.
__global__ __launch_bounds__(256) void norm_mask_kernel(const void* __restrict__ raw, int n,
                                                        int* __restrict__ outm) {
    const unsigned* as_u = (const unsigned*)raw;
    const float* as_f = (const float*)raw;
    const unsigned char* as_b = (const unsigned char*)raw;
    int ns = n < 512 ? n : 512;
    bool ok_i = true, ok_f = true;
    for (int i = 0; i < ns; ++i) {
        unsigned v = as_u[i];
        ok_i &= (v <= 1u);
        ok_f &= (v == 0u) || (v == 0x3f800000u);
    }
    const int mode = ok_i ? 0 : (ok_f ? 1 : 2);
    int i = blockIdx.x * 256 + threadIdx.x;
    if (i < n) {
        int v;
        if (mode == 0) v = (int)as_u[i];
        else if (mode == 1) v = (as_f[i] != 0.f) ? 1 : 0;
        else v = (int)as_b[i];
        outm[i] = (v != 0) ? 1 : 0;
    }
}

// ===== MFMA QKV GEMM, m97-style: global_load_lds w16, linear LDS, BK=32 =====
// C[m][f] = sum_k A[m][k] * W[f][k]
__global__ __launch_bounds__(256, 2) void qkv_gemm_kernel(const u16* __restrict__ A,
                                                          const u16* __restrict__ Bw,
                                                          u16* __restrict__ C) {
    __shared__ u16 As[128 * 32];   // linear, row stride 32 u16 (64 B)
    __shared__ u16 Bs[128 * 32];
    const int t = threadIdx.x;
    const int lane = t & 63;
    const int wave = t >> 6;
    const int wr = (wave >> 1) * 64;
    const int wc = (wave & 1) * 64;
    const int row0 = blockIdx.x * 128;
    const int col0 = blockIdx.y * 128;

    const int lr = lane & 15;          // A/B frag row index
    const int lk = (lane >> 4) * 8;    // frag k offset (u16)
    const int cr = (lane >> 4) * 4;    // C frag row base
    const int cc = lane & 15;          // C frag col

    const f32x4 fzero = {0.f, 0.f, 0.f, 0.f};
    f32x4 acc[4][4];
#pragma unroll
    for (int i = 0; i < 4; ++i)
#pragma unroll
        for (int j = 0; j < 4; ++j) acc[i][j] = fzero;

    const int strow = wave * 16 + (lane >> 2);
    const int stcol = (lane & 3) * 8;   // u16 col within 32-u16 row

    for (int k0 = 0; k0 < DIMc; k0 += 32) {
        __syncthreads();
#pragma unroll
        for (int issue = 0; issue < 2; ++issue) {
            const int r = issue * 64 + strow;
            __builtin_amdgcn_global_load_lds(
                (gl_u32*)(A + (size_t)(row0 + r) * DIMc + k0 + stcol),
                (lds_u32*)(As + (size_t)(issue * 64 + wave * 16) * 32), 16, 0, 0);
            __builtin_amdgcn_global_load_lds(
                (gl_u32*)(Bw + (size_t)(col0 + r) * DIMc + k0 + stcol),
                (lds_u32*)(Bs + (size_t)(issue * 64 + wave * 16) * 32), 16, 0, 0);
        }
        __syncthreads();

        bf16x8 af[4], bfr[4];
#pragma unroll
        for (int i = 0; i < 4; ++i) {
            af[i]  = *reinterpret_cast<const bf16x8*>(&As[(wr + i * 16 + lr) * 32 + lk]);
            bfr[i] = *reinterpret_cast<const bf16x8*>(&Bs[(wc + i * 16 + lr) * 32 + lk]);
        }
#pragma unroll
        for (int mi = 0; mi < 4; ++mi)
#pragma unroll
            for (int ni = 0; ni < 4; ++ni)
                acc[mi][ni] = __builtin_amdgcn_mfma_f32_16x16x32_bf16(af[mi], bfr[ni], acc[mi][ni], 0, 0, 0);
    }

#pragma unroll
    for (int mi = 0; mi < 4; ++mi)
#pragma unroll
        for (int ni = 0; ni < 4; ++ni)
#pragma unroll
            for (int j = 0; j < 4; ++j) {
                int r = row0 + wr + mi * 16 + cr + j;
                int c = col0 + wc + ni * 16 + cc;
                C[(size_t)r * F3 + c] = f2b(acc[mi][ni][j]);
            }
}

// ===== per-16-row-tile attention compute =====
static __device__ __forceinline__ void attn_tile_compute(
    const bf16x8 (&qfr)[2], int qmv,
    float& mrow, float& lsum, f32x4 (&oacc)[4],
    const bf16x8 (&ka)[4][2], const bf16x8 (&va)[4][2],
    const int (&km)[4][4],
    int wq0, int m0, int causal,
    u16 (*Psw)[KPAD], int g, int lq)
{
    const f32x4 fzero = {0.f, 0.f, 0.f, 0.f};
    // S^T = K Q^T : lane holds q = lq, k = kf*16 + g*4 + r
    f32x4 sacc[4];
#pragma unroll
    for (int kf = 0; kf < 4; ++kf) sacc[kf] = fzero;
#pragma unroll
    for (int kf = 0; kf < 4; ++kf) {
        sacc[kf] = __builtin_amdgcn_mfma_f32_16x16x32_bf16(ka[kf][0], qfr[0], sacc[kf], 0, 0, 0);
        sacc[kf] = __builtin_amdgcn_mfma_f32_16x16x32_bf16(ka[kf][1], qfr[1], sacc[kf], 0, 0, 0);
    }

    const int qg = wq0 + lq;
    const bool qok = (qmv != 0);
    float s[4][4];
    float mx = -1e30f;
#pragma unroll
    for (int kf = 0; kf < 4; ++kf)
#pragma unroll
        for (int r = 0; r < 4; ++r) {
            const int kg = m0 + kf * 16 + g * 4 + r;
            float sv = sacc[kf][r] * 0.125f;   // 1/sqrt(64)
            const bool ok = qok && (km[kf][r] != 0) && (!causal || kg <= qg);
            sv = ok ? sv : -1e30f;
            s[kf][r] = sv;
            mx = fmaxf(mx, sv);
        }
    mx = fmaxf(mx, __shfl_xor(mx, 16));
    mx = fmaxf(mx, __shfl_xor(mx, 32));
    const float mnew = fmaxf(mrow, mx);
    const float scale = __expf(mrow - mnew);
    float rs = 0.f;
#pragma unroll
    for (int kf = 0; kf < 4; ++kf)
#pragma unroll
        for (int r = 0; r < 4; ++r) {
            const float pv = (s[kf][r] > -1e29f) ? __expf(s[kf][r] - mnew) : 0.f;
            s[kf][r] = pv;
            rs += pv;
        }
    rs += __shfl_xor(rs, 16);
    rs += __shfl_xor(rs, 32);
    lsum = lsum * scale + rs;
    mrow = mnew;
#pragma unroll
    for (int df = 0; df < 4; ++df) oacc[df] *= scale;
#pragma unroll
    for (int kf = 0; kf < 4; ++kf)
#pragma unroll
        for (int r = 0; r < 4; ++r)
            Psw[lq][kf * 16 + g * 4 + r] = f2b(s[kf][r]);

    // O^T += V^T P^T (Psw is wave-local; no barrier needed)
    bf16x8 pb[2];
#pragma unroll
    for (int kc = 0; kc < 2; ++kc)
        pb[kc] = *reinterpret_cast<const bf16x8*>(&Psw[lq][kc * 32 + g * 8]);
#pragma unroll
    for (int df = 0; df < 4; ++df) {
        oacc[df] = __builtin_amdgcn_mfma_f32_16x16x32_bf16(va[df][0], pb[0], oacc[df], 0, 0, 0);
        oacc[df] = __builtin_amdgcn_mfma_f32_16x16x32_bf16(va[df][1], pb[1], oacc[df], 0, 0, 0);
    }
}

// ===== MFMA flash attention: paired 64-row q-slots (p, 31-p), 1024 equal-work blocks =====
// Block = (b, h, pair p in 0..15). 4 waves x 16 q-rows per tile. Output f32.
__global__ __launch_bounds__(256, 4) void attn_kernel(const u16* __restrict__ qkv,
                                                      const int* __restrict__ key_mask,
                                                      const int* __restrict__ query_mask,
                                                      const int* __restrict__ causal_p,
                                                      float* __restrict__ out) {
    const int bh = blockIdx.x;
    const int p = blockIdx.y;           // 0..15
    const int b = bh >> 4;
    const int h = bh & 15;
    const int t = threadIdx.x;
    const int lane = t & 63;
    const int wave = t >> 6;
    const int g = lane >> 4;
    const int lq = lane & 15;
    const int causal = causal_p[0];

    __shared__ u16 Ks[64][KPAD];
    __shared__ u16 Vt[64][KPAD];
    __shared__ u16 Ps[4][16][KPAD];

    const int q0A = p * 64;
    const int q0B = (31 - p) * 64;
    const int wq0A = q0A + wave * 16;
    const int wq0B = q0B + wave * 16;

    const f32x4 fzero = {0.f, 0.f, 0.f, 0.f};

    bf16x8 qfrA[2], qfrB[2];
#pragma unroll
    for (int ks = 0; ks < 2; ++ks) {
        qfrA[ks] = *reinterpret_cast<const bf16x8*>(
            qkv + (size_t)(b * Nseq + wq0A + lq) * F3 + h * HD + ks * 32 + g * 8);
        qfrB[ks] = *reinterpret_cast<const bf16x8*>(
            qkv + (size_t)(b * Nseq + wq0B + lq) * F3 + h * HD + ks * 32 + g * 8);
    }

    const int qmA = query_mask[b * Nseq + wq0A + lq];
    const int qmB = query_mask[b * Nseq + wq0B + lq];
    float mrowA = -1e30f, lsumA = 0.f, mrowB = -1e30f, lsumB = 0.f;
    f32x4 oaccA[4], oaccB[4];
#pragma unroll
    for (int df = 0; df < 4; ++df) { oaccA[df] = fzero; oaccB[df] = fzero; }

    const int kvendA = causal ? (q0A + 64) : Nseq;
    const int kvendB = causal ? (q0B + 64) : Nseq;   // >= kvendA

    const int sr = t >> 2;           // K staging row 0..63
    const int sc = (t & 3) * 8;      // K staging col {0,8,16,24}

    // prologue: load K/V for m0 = 0 into registers
    bf16x8 kr0, kr1, vr0, vr1;
    {
        const u16* krow = qkv + (size_t)(b * Nseq + sr) * F3 + DIMc + h * HD;
        kr0 = *reinterpret_cast<const bf16x8*>(krow + sc);
        kr1 = *reinterpret_cast<const bf16x8*>(krow + sc + 32);
        const u16* vrow = qkv + (size_t)(b * Nseq + lane) * F3 + 2 * DIMc + h * HD + wave * 16;
        vr0 = *reinterpret_cast<const bf16x8*>(vrow);
        vr1 = *reinterpret_cast<const bf16x8*>(vrow + 8);
    }

    for (int m0 = 0; m0 < kvendB; m0 += 64) {
        // ---- write staged regs -> LDS ----
        *reinterpret_cast<bf16x8*>(&Ks[sr][sc])      = kr0;
        *reinterpret_cast<bf16x8*>(&Ks[sr][sc + 32]) = kr1;
#pragma unroll
        for (int e = 0; e < 8; ++e) {
            Vt[wave * 16 + e][lane]     = (u16)vr0[e];
            Vt[wave * 16 + 8 + e][lane] = (u16)vr1[e];
        }
        __syncthreads();

        // ---- prefetch next tile into registers (drains under compute) ----
        if (m0 + 64 < kvendB) {
            const u16* krow = qkv + (size_t)(b * Nseq + m0 + 64 + sr) * F3 + DIMc + h * HD;
            kr0 = *reinterpret_cast<const bf16x8*>(krow + sc);
            kr1 = *reinterpret_cast<const bf16x8*>(krow + sc + 32);
            const u16* vrow = qkv + (size_t)(b * Nseq + m0 + 64 + lane) * F3 + 2 * DIMc + h * HD + wave * 16;
            vr0 = *reinterpret_cast<const bf16x8*>(vrow);
            vr1 = *reinterpret_cast<const bf16x8*>(vrow + 8);
        }

        // ---- shared per-iteration loads ----
        int km[4][4];
#pragma unroll
        for (int kf = 0; kf < 4; ++kf) {
            int4 k4 = *reinterpret_cast<const int4*>(key_mask + b * Nseq + m0 + kf * 16 + g * 4);
            km[kf][0] = k4.x; km[kf][1] = k4.y; km[kf][2] = k4.z; km[kf][3] = k4.w;
        }
        bf16x8 ka[4][2], va[4][2];
#pragma unroll
        for (int kf = 0; kf < 4; ++kf)
#pragma unroll
            for (int ks = 0; ks < 2; ++ks)
                ka[kf][ks] = *reinterpret_cast<const bf16x8*>(&Ks[kf * 16 + lq][ks * 32 + g * 8]);
#pragma unroll
        for (int df = 0; df < 4; ++df)
#pragma unroll
            for (int kc = 0; kc < 2; ++kc)
                va[df][kc] = *reinterpret_cast<const bf16x8*>(&Vt[df * 16 + lq][kc * 32 + g * 8]);

        // ---- tile B (longer range), then tile A while in causal range ----
        attn_tile_compute(qfrB, qmB, mrowB, lsumB, oaccB, ka, va, km, wq0B, m0, causal,
                          Ps[wave], g, lq);
        if (m0 < kvendA)
            attn_tile_compute(qfrA, qmA, mrowA, lsumA, oaccA, ka, va, km, wq0A, m0, causal,
                              Ps[wave], g, lq);
        __syncthreads();
    }

    // ---- epilogue ----
    {
        const float invA = (mrowA > -1e29f && lsumA > 0.f) ? 1.f / lsumA : 0.f;
        const float invB = (mrowB > -1e29f && lsumB > 0.f) ? 1.f / lsumB : 0.f;
        const size_t rowA = (size_t)(b * Nseq + wq0A + lq) * DIMc + h * HD;
        const size_t rowB = (size_t)(b * Nseq + wq0B + lq) * DIMc + h * HD;
#pragma unroll
        for (int df = 0; df < 4; ++df)
#pragma unroll
            for (int r = 0; r < 4; ++r) {
                out[rowA + df * 16 + g * 4 + r] = oaccA[df][r] * invA;
                out[rowB + df * 16 + g * 4 + r] = oaccB[df][r] * invB;
            }
    }
}

extern "C" void kernel_launch(void* const* d_in, const int* in_sizes, int n_in,
                              void* d_out, int out_size, void* d_ws, size_t ws_size,
                              hipStream_t stream) {
    const float* x = (const float*)d_in[0];       // [4,2048,1024] f32
    const float* W = (const float*)d_in[1];       // [3072,1024] f32

    char* ws = (char*)d_ws;
    int* km_n = (int*)(ws);
    int* qm_n = (int*)(ws + 32 * 1024);
    int* ca_n = (int*)(ws + 64 * 1024);
    u16* qkv  = (u16*)(ws + (size_t)1024 * 1024);             // 48 MiB
    u16* xb   = (u16*)(ws + (size_t)49 * 1024 * 1024);        // 16 MiB
    u16* wb   = (u16*)(ws + (size_t)65 * 1024 * 1024);        //  6 MiB

    const int nm = Bdim * Nseq;
    norm_mask_kernel<<<(nm + 255) / 256, 256, 0, stream>>>(d_in[2], nm, km_n);
    norm_mask_kernel<<<(nm + 255) / 256, 256, 0, stream>>>(d_in[3], nm, qm_n);
    norm_mask_kernel<<<1, 256, 0, stream>>>(d_in[4], 1, ca_n);

    const int nx4 = (Mrows * DIMc) / 4;
    const int nw4 = (F3 * DIMc) / 4;
    cast_f32_bf16_kernel<<<(nx4 + 255) / 256, 256, 0, stream>>>(x, xb, nx4);
    cast_f32_bf16_kernel<<<(nw4 + 255) / 256, 256, 0, stream>>>(W, wb, nw4);

    qkv_gemm_kernel<<<dim3(Mrows / 128, F3 / 128), 256, 0, stream>>>(xb, wb, qkv);

    attn_kernel<<<dim3(Bdim * NH, 16), 256, 0, stream>>>(qkv, km_n, qm_n, ca_n,
                                                         (float*)d_out);
}

// Round 9
// 261.222 us; speedup vs baseline: 2.1367x; 2.1367x over previous
//
#include <hip/hip_runtime.h>
#include <hip/hip_bf16.h>

typedef unsigned short u16;
typedef __attribute__((ext_vector_type(8))) short bf16x8;   // 8 bf16 (4 VGPRs)
typedef __attribute__((ext_vector_type(4))) float f32x4;

#define Bdim 4
#define Nseq 2048
#define DIMc 1024
#define NH   16
#define HD   64
#define F3   3072   // 3*NH*HD
#define Mrows 8192  // Bdim*Nseq

#define KPAD 68     // LDS row stride in u16: 136 B = 34 dwords -> 2-way banks (free)

typedef const __attribute__((address_space(1))) unsigned int gl_u32;
typedef __attribute__((address_space(3))) unsigned int lds_u32;

// f32 -> bf16 RNE
static __device__ __forceinline__ u16 f2b(float f) {
    union { float f; unsigned u; } v; v.f = f;
    unsigned r = v.u + 0x7fffu + ((v.u >> 16) & 1u);
    return (u16)(r >> 16);
}

__global__ __launch_bounds__(256) void cast_f32_bf16_kernel(const float* __restrict__ in,
                                                            u16* __restrict__ out, int n4) {
    int i = blockIdx.x * 256 + threadIdx.x;
    if (i >= n4) return;
    float4 v = reinterpret_cast<const float4*>(in)[i];
    ushort4 o;
    o.x = f2b(v.x); o.y = f2b(v.y); o.z = f2b(v.z); o.w = f2b(v.w);
    reinterpret_cast<ushort4*>(out)[i] = o;
}

// Normalize a 0/1 mask buffer of unknown dtype (int32 / float32 / uint8) to int32.
__global__ __launch_bounds__(256) void norm_mask_kernel(const void* __restrict__ raw, int n,
                                                        int* __restrict__ outm) {
    const unsigned* as_u = (const unsigned*)raw;
    const float* as_f = (const float*)raw;
    const unsigned char* as_b = (const unsigned char*)raw;
    int ns = n < 512 ? n : 512;
    bool ok_i = true, ok_f = true;
    for (int i = 0; i < ns; ++i) {
        unsigned v = as_u[i];
        ok_i &= (v <= 1u);
        ok_f &= (v == 0u) || (v == 0x3f800000u);
    }
    const int mode = ok_i ? 0 : (ok_f ? 1 : 2);
    int i = blockIdx.x * 256 + threadIdx.x;
    if (i < n) {
        int v;
        if (mode == 0) v = (int)as_u[i];
        else if (mode == 1) v = (as_f[i] != 0.f) ? 1 : 0;
        else v = (int)as_b[i];
        outm[i] = (v != 0) ? 1 : 0;
    }
}

// ===== MFMA QKV GEMM, m97-style: global_load_lds w16, linear LDS, BK=32 =====
// C[m][f] = sum_k A[m][k] * W[f][k]
__global__ __launch_bounds__(256, 2) void qkv_gemm_kernel(const u16* __restrict__ A,
                                                          const u16* __restrict__ Bw,
                                                          u16* __restrict__ C) {
    __shared__ u16 As[128 * 32];   // linear, row stride 32 u16 (64 B)
    __shared__ u16 Bs[128 * 32];
    const int t = threadIdx.x;
    const int lane = t & 63;
    const int wave = t >> 6;
    const int wr = (wave >> 1) * 64;
    const int wc = (wave & 1) * 64;
    const int row0 = blockIdx.x * 128;
    const int col0 = blockIdx.y * 128;

    const int lr = lane & 15;          // A/B frag row index
    const int lk = (lane >> 4) * 8;    // frag k offset (u16)
    const int cr = (lane >> 4) * 4;    // C frag row base
    const int cc = lane & 15;          // C frag col

    const f32x4 fzero = {0.f, 0.f, 0.f, 0.f};
    f32x4 acc[4][4];
#pragma unroll
    for (int i = 0; i < 4; ++i)
#pragma unroll
        for (int j = 0; j < 4; ++j) acc[i][j] = fzero;

    const int strow = wave * 16 + (lane >> 2);
    const int stcol = (lane & 3) * 8;   // u16 col within 32-u16 row

    for (int k0 = 0; k0 < DIMc; k0 += 32) {
        __syncthreads();
#pragma unroll
        for (int issue = 0; issue < 2; ++issue) {
            const int r = issue * 64 + strow;
            __builtin_amdgcn_global_load_lds(
                (gl_u32*)(A + (size_t)(row0 + r) * DIMc + k0 + stcol),
                (lds_u32*)(As + (size_t)(issue * 64 + wave * 16) * 32), 16, 0, 0);
            __builtin_amdgcn_global_load_lds(
                (gl_u32*)(Bw + (size_t)(col0 + r) * DIMc + k0 + stcol),
                (lds_u32*)(Bs + (size_t)(issue * 64 + wave * 16) * 32), 16, 0, 0);
        }
        __syncthreads();

        bf16x8 af[4], bfr[4];
#pragma unroll
        for (int i = 0; i < 4; ++i) {
            af[i]  = *reinterpret_cast<const bf16x8*>(&As[(wr + i * 16 + lr) * 32 + lk]);
            bfr[i] = *reinterpret_cast<const bf16x8*>(&Bs[(wc + i * 16 + lr) * 32 + lk]);
        }
#pragma unroll
        for (int mi = 0; mi < 4; ++mi)
#pragma unroll
            for (int ni = 0; ni < 4; ++ni)
                acc[mi][ni] = __builtin_amdgcn_mfma_f32_16x16x32_bf16(af[mi], bfr[ni], acc[mi][ni], 0, 0, 0);
    }

#pragma unroll
    for (int mi = 0; mi < 4; ++mi)
#pragma unroll
        for (int ni = 0; ni < 4; ++ni)
#pragma unroll
            for (int j = 0; j < 4; ++j) {
                int r = row0 + wr + mi * 16 + cr + j;
                int c = col0 + wc + ni * 16 + cc;
                C[(size_t)r * F3 + c] = f2b(acc[mi][ni][j]);
            }
}

// ===== per-16-row-tile attention compute =====
static __device__ __forceinline__ void attn_tile_compute(
    const bf16x8 (&qfr)[2], int qmv,
    float& mrow, float& lsum, f32x4 (&oacc)[4],
    const bf16x8 (&ka)[4][2], const bf16x8 (&va)[4][2],
    const int (&km)[4][4],
    int wq0, int m0, int causal,
    u16 (*Psw)[KPAD], int g, int lq)
{
    const f32x4 fzero = {0.f, 0.f, 0.f, 0.f};
    // S^T = K Q^T : lane holds q = lq, k = kf*16 + g*4 + r
    f32x4 sacc[4];
#pragma unroll
    for (int kf = 0; kf < 4; ++kf) sacc[kf] = fzero;
#pragma unroll
    for (int kf = 0; kf < 4; ++kf) {
        sacc[kf] = __builtin_amdgcn_mfma_f32_16x16x32_bf16(ka[kf][0], qfr[0], sacc[kf], 0, 0, 0);
        sacc[kf] = __builtin_amdgcn_mfma_f32_16x16x32_bf16(ka[kf][1], qfr[1], sacc[kf], 0, 0, 0);
    }

    const int qg = wq0 + lq;
    const bool qok = (qmv != 0);
    float s[4][4];
    float mx = -1e30f;
#pragma unroll
    for (int kf = 0; kf < 4; ++kf)
#pragma unroll
        for (int r = 0; r < 4; ++r) {
            const int kg = m0 + kf * 16 + g * 4 + r;
            float sv = sacc[kf][r] * 0.125f;   // 1/sqrt(64)
            const bool ok = qok && (km[kf][r] != 0) && (!causal || kg <= qg);
            sv = ok ? sv : -1e30f;
            s[kf][r] = sv;
            mx = fmaxf(mx, sv);
        }
    mx = fmaxf(mx, __shfl_xor(mx, 16));
    mx = fmaxf(mx, __shfl_xor(mx, 32));
    const float mnew = fmaxf(mrow, mx);
    const float scale = __expf(mrow - mnew);
    float rs = 0.f;
#pragma unroll
    for (int kf = 0; kf < 4; ++kf)
#pragma unroll
        for (int r = 0; r < 4; ++r) {
            const float pv = (s[kf][r] > -1e29f) ? __expf(s[kf][r] - mnew) : 0.f;
            s[kf][r] = pv;
            rs += pv;
        }
    rs += __shfl_xor(rs, 16);
    rs += __shfl_xor(rs, 32);
    lsum = lsum * scale + rs;
    mrow = mnew;
#pragma unroll
    for (int df = 0; df < 4; ++df) oacc[df] *= scale;
#pragma unroll
    for (int kf = 0; kf < 4; ++kf)
#pragma unroll
        for (int r = 0; r < 4; ++r)
            Psw[lq][kf * 16 + g * 4 + r] = f2b(s[kf][r]);

    // O^T += V^T P^T (Psw is wave-local; no barrier needed)
    bf16x8 pb[2];
#pragma unroll
    for (int kc = 0; kc < 2; ++kc)
        pb[kc] = *reinterpret_cast<const bf16x8*>(&Psw[lq][kc * 32 + g * 8]);
#pragma unroll
    for (int df = 0; df < 4; ++df) {
        oacc[df] = __builtin_amdgcn_mfma_f32_16x16x32_bf16(va[df][0], pb[0], oacc[df], 0, 0, 0);
        oacc[df] = __builtin_amdgcn_mfma_f32_16x16x32_bf16(va[df][1], pb[1], oacc[df], 0, 0, 0);
    }
}

// ===== MFMA flash attention: paired 64-row q-slots (p, 31-p), 1024 equal-work blocks =====
// Block = (b, h, pair p in 0..15). 4 waves x 16 q-rows per tile. Output f32.
// NOTE: (256,2) launch bounds — (256,4) forced VGPR=64 and catastrophic spills (r8).
__global__ __launch_bounds__(256, 2) void attn_kernel(const u16* __restrict__ qkv,
                                                      const int* __restrict__ key_mask,
                                                      const int* __restrict__ query_mask,
                                                      const int* __restrict__ causal_p,
                                                      float* __restrict__ out) {
    const int bh = blockIdx.x;
    const int p = blockIdx.y;           // 0..15
    const int b = bh >> 4;
    const int h = bh & 15;
    const int t = threadIdx.x;
    const int lane = t & 63;
    const int wave = t >> 6;
    const int g = lane >> 4;
    const int lq = lane & 15;
    const int causal = causal_p[0];

    __shared__ u16 Ks[64][KPAD];
    __shared__ u16 Vt[64][KPAD];
    __shared__ u16 Ps[4][16][KPAD];

    const int q0A = p * 64;
    const int q0B = (31 - p) * 64;
    const int wq0A = q0A + wave * 16;
    const int wq0B = q0B + wave * 16;

    const f32x4 fzero = {0.f, 0.f, 0.f, 0.f};

    bf16x8 qfrA[2], qfrB[2];
#pragma unroll
    for (int ks = 0; ks < 2; ++ks) {
        qfrA[ks] = *reinterpret_cast<const bf16x8*>(
            qkv + (size_t)(b * Nseq + wq0A + lq) * F3 + h * HD + ks * 32 + g * 8);
        qfrB[ks] = *reinterpret_cast<const bf16x8*>(
            qkv + (size_t)(b * Nseq + wq0B + lq) * F3 + h * HD + ks * 32 + g * 8);
    }

    const int qmA = query_mask[b * Nseq + wq0A + lq];
    const int qmB = query_mask[b * Nseq + wq0B + lq];
    float mrowA = -1e30f, lsumA = 0.f, mrowB = -1e30f, lsumB = 0.f;
    f32x4 oaccA[4], oaccB[4];
#pragma unroll
    for (int df = 0; df < 4; ++df) { oaccA[df] = fzero; oaccB[df] = fzero; }

    const int kvendA = causal ? (q0A + 64) : Nseq;
    const int kvendB = causal ? (q0B + 64) : Nseq;   // >= kvendA

    const int sr = t >> 2;           // K staging row 0..63
    const int sc = (t & 3) * 8;      // K staging col {0,8,16,24}

    // prologue: load K/V for m0 = 0 into registers
    bf16x8 kr0, kr1, vr0, vr1;
    {
        const u16* krow = qkv + (size_t)(b * Nseq + sr) * F3 + DIMc + h * HD;
        kr0 = *reinterpret_cast<const bf16x8*>(krow + sc);
        kr1 = *reinterpret_cast<const bf16x8*>(krow + sc + 32);
        const u16* vrow = qkv + (size_t)(b * Nseq + lane) * F3 + 2 * DIMc + h * HD + wave * 16;
        vr0 = *reinterpret_cast<const bf16x8*>(vrow);
        vr1 = *reinterpret_cast<const bf16x8*>(vrow + 8);
    }

    for (int m0 = 0; m0 < kvendB; m0 += 64) {
        // ---- write staged regs -> LDS ----
        *reinterpret_cast<bf16x8*>(&Ks[sr][sc])      = kr0;
        *reinterpret_cast<bf16x8*>(&Ks[sr][sc + 32]) = kr1;
#pragma unroll
        for (int e = 0; e < 8; ++e) {
            Vt[wave * 16 + e][lane]     = (u16)vr0[e];
            Vt[wave * 16 + 8 + e][lane] = (u16)vr1[e];
        }
        __syncthreads();

        // ---- prefetch next tile into registers (drains under compute) ----
        if (m0 + 64 < kvendB) {
            const u16* krow = qkv + (size_t)(b * Nseq + m0 + 64 + sr) * F3 + DIMc + h * HD;
            kr0 = *reinterpret_cast<const bf16x8*>(krow + sc);
            kr1 = *reinterpret_cast<const bf16x8*>(krow + sc + 32);
            const u16* vrow = qkv + (size_t)(b * Nseq + m0 + 64 + lane) * F3 + 2 * DIMc + h * HD + wave * 16;
            vr0 = *reinterpret_cast<const bf16x8*>(vrow);
            vr1 = *reinterpret_cast<const bf16x8*>(vrow + 8);
        }

        // ---- shared per-iteration loads ----
        int km[4][4];
#pragma unroll
        for (int kf = 0; kf < 4; ++kf) {
            int4 k4 = *reinterpret_cast<const int4*>(key_mask + b * Nseq + m0 + kf * 16 + g * 4);
            km[kf][0] = k4.x; km[kf][1] = k4.y; km[kf][2] = k4.z; km[kf][3] = k4.w;
        }
        bf16x8 ka[4][2], va[4][2];
#pragma unroll
        for (int kf = 0; kf < 4; ++kf)
#pragma unroll
            for (int ks = 0; ks < 2; ++ks)
                ka[kf][ks] = *reinterpret_cast<const bf16x8*>(&Ks[kf * 16 + lq][ks * 32 + g * 8]);
#pragma unroll
        for (int df = 0; df < 4; ++df)
#pragma unroll
            for (int kc = 0; kc < 2; ++kc)
                va[df][kc] = *reinterpret_cast<const bf16x8*>(&Vt[df * 16 + lq][kc * 32 + g * 8]);

        // ---- tile B (longer range), then tile A while in causal range ----
        attn_tile_compute(qfrB, qmB, mrowB, lsumB, oaccB, ka, va, km, wq0B, m0, causal,
                          Ps[wave], g, lq);
        if (m0 < kvendA)
            attn_tile_compute(qfrA, qmA, mrowA, lsumA, oaccA, ka, va, km, wq0A, m0, causal,
                              Ps[wave], g, lq);
        __syncthreads();
    }

    // ---- epilogue ----
    {
        const float invA = (mrowA > -1e29f && lsumA > 0.f) ? 1.f / lsumA : 0.f;
        const float invB = (mrowB > -1e29f && lsumB > 0.f) ? 1.f / lsumB : 0.f;
        const size_t rowA = (size_t)(b * Nseq + wq0A + lq) * DIMc + h * HD;
        const size_t rowB = (size_t)(b * Nseq + wq0B + lq) * DIMc + h * HD;
#pragma unroll
        for (int df = 0; df < 4; ++df)
#pragma unroll
            for (int r = 0; r < 4; ++r) {
                out[rowA + df * 16 + g * 4 + r] = oaccA[df][r] * invA;
                out[rowB + df * 16 + g * 4 + r] = oaccB[df][r] * invB;
            }
    }
}

extern "C" void kernel_launch(void* const* d_in, const int* in_sizes, int n_in,
                              void* d_out, int out_size, void* d_ws, size_t ws_size,
                              hipStream_t stream) {
    const float* x = (const float*)d_in[0];       // [4,2048,1024] f32
    const float* W = (const float*)d_in[1];       // [3072,1024] f32

    char* ws = (char*)d_ws;
    int* km_n = (int*)(ws);
    int* qm_n = (int*)(ws + 32 * 1024);
    int* ca_n = (int*)(ws + 64 * 1024);
    u16* qkv  = (u16*)(ws + (size_t)1024 * 1024);             // 48 MiB
    u16* xb   = (u16*)(ws + (size_t)49 * 1024 * 1024);        // 16 MiB
    u16* wb   = (u16*)(ws + (size_t)65 * 1024 * 1024);        //  6 MiB

    const int nm = Bdim * Nseq;
    norm_mask_kernel<<<(nm + 255) / 256, 256, 0, stream>>>(d_in[2], nm, km_n);
    norm_mask_kernel<<<(nm + 255) / 256, 256, 0, stream>>>(d_in[3], nm, qm_n);
    norm_mask_kernel<<<1, 256, 0, stream>>>(d_in[4], 1, ca_n);

    const int nx4 = (Mrows * DIMc) / 4;
    const int nw4 = (F3 * DIMc) / 4;
    cast_f32_bf16_kernel<<<(nx4 + 255) / 256, 256, 0, stream>>>(x, xb, nx4);
    cast_f32_bf16_kernel<<<(nw4 + 255) / 256, 256, 0, stream>>>(W, wb, nw4);

    qkv_gemm_kernel<<<dim3(Mrows / 128, F3 / 128), 256, 0, stream>>>(xb, wb, qkv);

    attn_kernel<<<dim3(Bdim * NH, 16), 256, 0, stream>>>(qkv, km_n, qm_n, ca_n,
                                                         (float*)d_out);
}